// Round 7
// baseline (261.957 us; speedup 1.0000x reference)
//
#include <hip/hip_runtime.h>
#include <stdint.h>

#define B_ 2
#define S_ 2048
#define D_ 1024
#define H_ 16
#define DQ_ 64
#define M_ 4096            // B_*S_

typedef unsigned short ushort_t;
typedef __attribute__((ext_vector_type(8))) short short8;    // 8 bf16 (4 VGPRs)
typedef __attribute__((ext_vector_type(4))) float floatx4;   // MFMA 16x16 C/D
typedef __attribute__((ext_vector_type(16))) float floatx16; // MFMA 32x32 C/D

#if __has_builtin(__builtin_amdgcn_exp2f)
#define EXP2(x) __builtin_amdgcn_exp2f(x)
#else
#define EXP2(x) exp2f(x)
#endif

__device__ __forceinline__ ushort_t f2bf(float f) {
  union { float f; uint32_t u; } v; v.f = f;
  uint32_t r = v.u + 0x7FFFu + ((v.u >> 16) & 1u);  // RNE
  return (ushort_t)(r >> 16);
}

// pack two f32 -> two bf16 (truncation; bias cancels in softmax ratio)
__device__ __forceinline__ uint32_t pk2_trunc(float a, float b) {
  union { float f; uint32_t u; } va, vb; va.f = a; vb.f = b;
  return (va.u >> 16) | (vb.u & 0xFFFF0000u);
}
__device__ __forceinline__ uint32_t pk2_rne(float a, float b) {
  return (uint32_t)f2bf(a) | ((uint32_t)f2bf(b) << 16);
}

__device__ __forceinline__ void async16(const ushort_t* g, ushort_t* l) {
  // LDS dest is wave-uniform base; HW scatters lane i at base + i*16B.
  __builtin_amdgcn_global_load_lds(
      (const __attribute__((address_space(1))) uint32_t*)g,
      (__attribute__((address_space(3))) uint32_t*)l, 16, 0, 0);
}

// ---------------- prep: fp32 -> bf16 casts ----------------

__global__ void k_cvt_emb(const float* __restrict__ in, ushort_t* __restrict__ out) {
  int i = (blockIdx.x * 256 + threadIdx.x) * 4;
  float4 v = *(const float4*)(in + i);
  uint64_t pk = (uint64_t)f2bf(v.x) | ((uint64_t)f2bf(v.y) << 16) |
                ((uint64_t)f2bf(v.z) << 32) | ((uint64_t)f2bf(v.w) << 48);
  *(uint64_t*)(out + i) = pk;
}

// W (k-major [k][n]) -> Wt bf16 (n-major [n][k]); 4 weights via blockIdx.z
__global__ void k_cvt_w(const float* __restrict__ Wq, const float* __restrict__ Wk,
                        const float* __restrict__ Wv, const float* __restrict__ Wo,
                        ushort_t* __restrict__ Wt) {
  const float* W = (blockIdx.z == 0) ? Wq : (blockIdx.z == 1) ? Wk
                 : (blockIdx.z == 2) ? Wv : Wo;
  ushort_t* out = Wt + (size_t)blockIdx.z * D_ * D_;
  __shared__ float t[32][33];
  int k0 = blockIdx.x * 32, n0 = blockIdx.y * 32;
  int tx = threadIdx.x, ty = threadIdx.y;  // block (32,8)
  for (int r = 0; r < 32; r += 8)
    t[ty + r][tx] = W[(size_t)(k0 + ty + r) * D_ + n0 + tx];
  __syncthreads();
  for (int r = 0; r < 32; r += 8)
    out[(size_t)(n0 + ty + r) * D_ + k0 + tx] = f2bf(t[tx][ty + r]);
}

// mask int32 -> additive bf16 bias in log2 domain:
// unmasked -> -16.0 (fixed softmax bound), masked -> -1e9 (exp2 underflows to 0)
__global__ void k_cvt_bias(const int* __restrict__ mask, ushort_t* __restrict__ biasK) {
  int i = blockIdx.x * 256 + threadIdx.x;
  biasK[i] = mask[i] ? 0xC180 : 0xCE6E;   // bf16(-16.0) : bf16(~-1e9)
}

// ---------------- swizzled bf16 NT GEMM core, BK=64 ----------------
// C[m][n] = sum_k A[m][k] * Bt[n][k]. Block tile: (IM*32) x 128, BK=64.
// LDS rows are 64 ushorts (8 chunks of 16B); chunk c of row r holds global
// chunk c ^ (r&7)  -> ds_read_b128 readers spread over all banks (conflict-free).
template <int IM>
__device__ __forceinline__ void gemm_core2(const ushort_t* __restrict__ A,
                                           const ushort_t* __restrict__ Bt,
                                           ushort_t* As, ushort_t* Bs,
                                           int m0, int n0, floatx4 (&acc)[IM][4]) {
  int t = threadIdx.x, lane = t & 63, w = t >> 6;
  int wm = (w >> 1) * (IM * 16), wn = (w & 1) * 64;
  int l15 = lane & 15, quad = lane >> 4;
  int srow8 = (lane >> 3) & 7;
  int sch = ((lane & 7) ^ srow8) * 8;                  // swizzled source chunk
  const ushort_t* Ag = A + (size_t)(m0 + w * 8 + srow8) * D_ + sch;
  const ushort_t* Bg = Bt + (size_t)(n0 + w * 8 + srow8) * D_ + sch;
  for (int kt = 0; kt < D_; kt += 64) {
    __syncthreads();
#pragma unroll
    for (int c = 0; c < IM; c++)
      async16(Ag + kt + (size_t)c * 32 * D_, As + (c * 32 + w * 8) * 64);
#pragma unroll
    for (int c = 0; c < 4; c++)
      async16(Bg + kt + (size_t)c * 32 * D_, Bs + (c * 32 + w * 8) * 64);
    __syncthreads();
#pragma unroll
    for (int ks = 0; ks < 2; ks++) {
      int ch = ((ks * 4 + quad) ^ (l15 & 7)) * 8;      // swizzled read chunk
      short8 a[IM], b[4];
#pragma unroll
      for (int i = 0; i < IM; i++)
        a[i] = *(const short8*)(As + (wm + i * 16 + l15) * 64 + ch);
#pragma unroll
      for (int j = 0; j < 4; j++)
        b[j] = *(const short8*)(Bs + (wn + j * 16 + l15) * 64 + ch);
#pragma unroll
      for (int i = 0; i < IM; i++)
#pragma unroll
        for (int j = 0; j < 4; j++)
          acc[i][j] = __builtin_amdgcn_mfma_f32_16x16x32_bf16(a[i], b[j], acc[i][j], 0, 0, 0);
    }
  }
}

// ---------------- QKV projection (z = 0/1/2 -> Q/K/V) ----------------
__global__ __launch_bounds__(256, 3) void k_proj(
    const ushort_t* __restrict__ A, const ushort_t* __restrict__ Wt,
    const float* __restrict__ bq, const float* __restrict__ bk,
    const float* __restrict__ bv,
    ushort_t* __restrict__ Q, ushort_t* __restrict__ K, ushort_t* __restrict__ V) {
  __shared__ __align__(16) ushort_t As[128 * 64];
  __shared__ __align__(16) ushort_t Bs[128 * 64];
  int z = blockIdx.z;
  const ushort_t* Bt = Wt + (size_t)z * D_ * D_;
  const float* bias = (z == 0) ? bq : (z == 1) ? bk : bv;
  int m0 = blockIdx.x * 128, n0 = blockIdx.y * 128;
  floatx4 acc[4][4] = {};
  gemm_core2<4>(A, Bt, As, Bs, m0, n0, acc);
  int lane = threadIdx.x & 63, w = threadIdx.x >> 6;
  int wm = (w >> 1) * 64, wn = (w & 1) * 64;
  int quad = lane >> 4, l15 = lane & 15;
  // fold 1/sqrt(DQ) * log2(e) into Q (scores end up in log2 domain)
  float scale = (z == 0) ? 0.125f * 1.44269504f : 1.0f;
#pragma unroll
  for (int i = 0; i < 4; i++)
#pragma unroll
    for (int j = 0; j < 4; j++) {
      int ncol = n0 + wn + j * 16 + l15;
      float bb = bias[ncol];
      int h = ncol >> 6, dq = ncol & 63;
      int m = m0 + wm + i * 16 + quad * 4;
      int b = m >> 11, s = m & (S_ - 1);
      if (z == 2) {
        // V^T [b,h,dq,s]: 4 r-values are consecutive s -> one 8B store
        uint64_t pk = (uint64_t)f2bf(acc[i][j][0] + bb) |
                      ((uint64_t)f2bf(acc[i][j][1] + bb) << 16) |
                      ((uint64_t)f2bf(acc[i][j][2] + bb) << 32) |
                      ((uint64_t)f2bf(acc[i][j][3] + bb) << 48);
        *(uint64_t*)(V + ((size_t)(b * H_ + h) * DQ_ + dq) * S_ + s) = pk;
      } else {
        ushort_t* dst = (z == 0) ? Q : K;
#pragma unroll
        for (int r = 0; r < 4; r++)
          dst[((size_t)(b * H_ + h) * S_ + (s + r)) * DQ_ + dq] =
              f2bf((acc[i][j][r] + bb) * scale);
      }
    }
}

// ---------------- flash attention: barrier-free, direct global fragments ----
// grid: (S_/128, B_*H_); block 256 = 4 independent waves; wave owns 32 q.
// 32x32x16 MFMA layouts (verified m74/m101 family):
//   A frag: m = lane&31, k = (lane>>5)*8 + j ;  B frag: n = lane&31, same k
//   C/D: col = lane&31, row = (reg&3) + 8*(reg>>2) + 4*(lane>>5)
// S^T = K·Q^T (+ bias MFMA step: masked keys -> -1e9 -> exp2 = 0 exactly).
// P^T stays in regs; half-swap via shfl_xor(32).  O^T = V^T·P^T.
__global__ __launch_bounds__(256, 2) void k_attn(
    const ushort_t* __restrict__ Q, const ushort_t* __restrict__ Kg,
    const ushort_t* __restrict__ Vt, const ushort_t* __restrict__ biasK,
    ushort_t* __restrict__ X) {
  int bh = blockIdx.y, b = bh >> 4, h = bh & 15;
  int t = threadIdx.x, lane = t & 63, w = t >> 6;
  int l31 = lane & 31, hi = lane >> 5;
  int q0 = blockIdx.x * 128 + w * 32;
  const ushort_t* Qh = Q + (size_t)bh * S_ * DQ_;
  const ushort_t* Kh = Kg + (size_t)bh * S_ * DQ_;
  const ushort_t* Vh = Vt + (size_t)bh * DQ_ * S_;
  const ushort_t* bbp = biasK + b * S_;

  // Q B-frags (pre-scaled by 0.125*log2e): per K=16 step, held for whole loop
  short8 qf[4];
#pragma unroll
  for (int ks = 0; ks < 4; ks++)
    qf[ks] = *(const short8*)(Qh + (size_t)(q0 + l31) * DQ_ + ks * 16 + hi * 8);

  // bias-step B-frag: ones at k=0 (hi==0, j==0)
  short8 qb = {};
  qb[0] = hi ? (short)0 : (short)0x3F80;   // bf16 1.0

  // per-lane fragment base pointers (advance by tile inside the loop)
  const ushort_t* Kp0 = Kh + (size_t)l31 * DQ_ + hi * 8;        // keys 0-31 rows
  const ushort_t* Kp1 = Kh + (size_t)(32 + l31) * DQ_ + hi * 8; // keys 32-63 rows
  const ushort_t* Vp0 = Vh + (size_t)l31 * S_ + hi * 8;         // dq 0-31 rows
  const ushort_t* Vp1 = Vh + (size_t)(32 + l31) * S_ + hi * 8;  // dq 32-63 rows

  floatx16 o[2] = {};
  float lsum = 0.0f;

  for (int k0 = 0; k0 < S_; k0 += 64) {
    // direct global fragment loads (compiler pipelines across iterations)
    short8 kf0[4], kf1[4], vf0[4], vf1[4];
#pragma unroll
    for (int ks = 0; ks < 4; ks++) {
      kf0[ks] = *(const short8*)(Kp0 + (size_t)k0 * DQ_ + ks * 16);
      kf1[ks] = *(const short8*)(Kp1 + (size_t)k0 * DQ_ + ks * 16);
      vf0[ks] = *(const short8*)(Vp0 + k0 + ks * 16);
      vf1[ks] = *(const short8*)(Vp1 + k0 + ks * 16);
    }
    ushort_t bv0 = bbp[k0 + l31], bv1 = bbp[k0 + 32 + l31];
    short8 kb0 = {}, kb1 = {};
    kb0[0] = hi ? (short)0 : (short)bv0;
    kb1[0] = hi ? (short)0 : (short)bv1;

    // S^T = K * Q^T  + bias step (col=q, row=key)
    floatx16 s0 = {}, s1 = {};
#pragma unroll
    for (int ks = 0; ks < 4; ks++) {
      s0 = __builtin_amdgcn_mfma_f32_32x32x16_bf16(kf0[ks], qf[ks], s0, 0, 0, 0);
      s1 = __builtin_amdgcn_mfma_f32_32x32x16_bf16(kf1[ks], qf[ks], s1, 0, 0, 0);
    }
    s0 = __builtin_amdgcn_mfma_f32_32x32x16_bf16(kb0, qb, s0, 0, 0, 0);
    s1 = __builtin_amdgcn_mfma_f32_32x32x16_bf16(kb1, qb, s1, 0, 0, 0);

    // p = 2^s (bias already folded in); pack to bf16 dwords in registers.
    // reg r=4g+j of acc a holds key = a*32 + 8g + 4*hi + j  (col q = l31)
    uint32_t pk[2][4][2];
#pragma unroll
    for (int g = 0; g < 4; g++) {
      float p0[4], p1[4];
#pragma unroll
      for (int j = 0; j < 4; j++) {
        p0[j] = EXP2(s0[g * 4 + j]);
        p1[j] = EXP2(s1[g * 4 + j]);
        lsum += p0[j] + p1[j];
      }
      pk[0][g][0] = pk2_trunc(p0[0], p0[1]); pk[0][g][1] = pk2_trunc(p0[2], p0[3]);
      pk[1][g][0] = pk2_trunc(p1[0], p1[1]); pk[1][g][1] = pk2_trunc(p1[2], p1[3]);
    }

    // O^T += V^T * P^T : A = V^T rows (dq), B = P^T built from regs.
    // Frag ks needs keys ks*16 + hi*8 + {0..7}; partner half via shfl_xor(32).
#pragma unroll
    for (int ks = 0; ks < 4; ks++) {
      int a = ks >> 1, gb = (ks & 1) * 2;
      uint32_t pass0 = hi ? pk[a][gb][0]     : pk[a][gb + 1][0];
      uint32_t pass1 = hi ? pk[a][gb][1]     : pk[a][gb + 1][1];
      uint32_t own0  = hi ? pk[a][gb + 1][0] : pk[a][gb][0];
      uint32_t own1  = hi ? pk[a][gb + 1][1] : pk[a][gb][1];
      uint32_t recv0 = __shfl_xor(pass0, 32, 64);
      uint32_t recv1 = __shfl_xor(pass1, 32, 64);
      union { uint32_t u[4]; short8 v; } pf;
      pf.u[0] = hi ? recv0 : own0;   // hi_src=0: keys +0..3
      pf.u[1] = hi ? recv1 : own1;
      pf.u[2] = hi ? own0 : recv0;   // hi_src=1: keys +4..7
      pf.u[3] = hi ? own1 : recv1;
      o[0] = __builtin_amdgcn_mfma_f32_32x32x16_bf16(vf0[ks], pf.v, o[0], 0, 0, 0);
      o[1] = __builtin_amdgcn_mfma_f32_32x32x16_bf16(vf1[ks], pf.v, o[1], 0, 0, 0);
    }
  }

  // epilogue: l(q) = own-half sum + partner-half sum; packed 8B stores
  float l = lsum + __shfl_xor(lsum, 32, 64);
  float inv = 1.0f / l;
  int q = q0 + l31;
  size_t base = (size_t)(b * S_ + q) * D_ + h * DQ_;
#pragma unroll
  for (int a = 0; a < 2; a++)
#pragma unroll
    for (int g = 0; g < 4; g++) {
      uint2 st;
      st.x = pk2_rne(o[a][4 * g] * inv, o[a][4 * g + 1] * inv);
      st.y = pk2_rne(o[a][4 * g + 2] * inv, o[a][4 * g + 3] * inv);
      *(uint2*)(X + base + a * 32 + g * 8 + 4 * hi) = st;
    }
}

// ---------------- output projection (fp32 out), 64x128 tile ----------------
__global__ __launch_bounds__(256, 2) void k_oproj(
    const ushort_t* __restrict__ A, const ushort_t* __restrict__ Wt,
    const float* __restrict__ bias, float* __restrict__ C) {
  __shared__ __align__(16) ushort_t As[64 * 64];
  __shared__ __align__(16) ushort_t Bs[128 * 64];
  int m0 = blockIdx.x * 64, n0 = blockIdx.y * 128;
  floatx4 acc[2][4] = {};
  gemm_core2<2>(A, Wt, As, Bs, m0, n0, acc);
  int lane = threadIdx.x & 63, w = threadIdx.x >> 6;
  int wm = (w >> 1) * 32, wn = (w & 1) * 64;
  int quad = lane >> 4, l15 = lane & 15;
#pragma unroll
  for (int i = 0; i < 2; i++)
#pragma unroll
    for (int j = 0; j < 4; j++) {
      int ncol = n0 + wn + j * 16 + l15;
      float bb = bias[ncol];
      int mr = m0 + wm + i * 16 + quad * 4;
#pragma unroll
      for (int r = 0; r < 4; r++)
        C[(size_t)(mr + r) * D_ + ncol] = acc[i][j][r] + bb;
    }
}

extern "C" void kernel_launch(void* const* d_in, const int* in_sizes, int n_in,
                              void* d_out, int out_size, void* d_ws, size_t ws_size,
                              hipStream_t stream) {
  const float* emb  = (const float*)d_in[0];
  const int*   mask = (const int*)d_in[1];
  const float* Wq = (const float*)d_in[2];
  const float* bq = (const float*)d_in[3];
  const float* Wk = (const float*)d_in[4];
  const float* bk = (const float*)d_in[5];
  const float* Wv = (const float*)d_in[6];
  const float* bv = (const float*)d_in[7];
  const float* Wo = (const float*)d_in[8];
  const float* bo = (const float*)d_in[9];
  float* out = (float*)d_out;

  ushort_t* embb = (ushort_t*)d_ws;                 // 4096x1024 bf16
  ushort_t* Wt   = embb + (size_t)M_ * D_;          // 4 x 1024x1024 bf16 (transposed)
  ushort_t* Qb   = Wt + (size_t)4 * D_ * D_;        // [b,h,s,dq]  (pre-scaled)
  ushort_t* Kb   = Qb + (size_t)M_ * D_;            // [b,h,s,dq]
  ushort_t* Vb   = Kb + (size_t)M_ * D_;            // [b,h,dq,s]  (V^T)
  ushort_t* Xb   = Vb + (size_t)M_ * D_;            // [b*s, h*dq]
  ushort_t* Bi   = Xb + (size_t)M_ * D_;            // bf16 additive mask bias [B_][S_]

  k_cvt_emb<<<dim3(M_ * D_ / 1024), 256, 0, stream>>>(emb, embb);
  k_cvt_w<<<dim3(32, 32, 4), dim3(32, 8), 0, stream>>>(Wq, Wk, Wv, Wo, Wt);
  k_cvt_bias<<<dim3(B_ * S_ / 256), 256, 0, stream>>>(mask, Bi);
  k_proj<<<dim3(32, 8, 3), 256, 0, stream>>>(embb, Wt, bq, bk, bv, Qb, Kb, Vb);
  k_attn<<<dim3(16, 32), 256, 0, stream>>>(Qb, Kb, Vb, Bi, Xb);
  k_oproj<<<dim3(64, 8), 256, 0, stream>>>(Xb, Wt + (size_t)3 * D_ * D_, bo, out);
}

// Round 8
// 186.312 us; speedup vs baseline: 1.4060x; 1.4060x over previous
//
#include <hip/hip_runtime.h>
#include <stdint.h>

#define B_ 2
#define S_ 2048
#define D_ 1024
#define H_ 16
#define DQ_ 64
#define M_ 4096            // B_*S_

typedef unsigned short ushort_t;
typedef __attribute__((ext_vector_type(8))) short short8;    // 8 bf16 (4 VGPRs)
typedef __attribute__((ext_vector_type(4))) float floatx4;   // MFMA 16x16 C/D
typedef __attribute__((ext_vector_type(16))) float floatx16; // MFMA 32x32 C/D

#if __has_builtin(__builtin_amdgcn_exp2f)
#define EXP2(x) __builtin_amdgcn_exp2f(x)
#else
#define EXP2(x) exp2f(x)
#endif

__device__ __forceinline__ ushort_t f2bf(float f) {
  union { float f; uint32_t u; } v; v.f = f;
  uint32_t r = v.u + 0x7FFFu + ((v.u >> 16) & 1u);  // RNE
  return (ushort_t)(r >> 16);
}

// pack two f32 -> two bf16 (truncation; bias cancels in softmax ratio)
__device__ __forceinline__ uint32_t pk2_trunc(float a, float b) {
  union { float f; uint32_t u; } va, vb; va.f = a; vb.f = b;
  return (va.u >> 16) | (vb.u & 0xFFFF0000u);
}
__device__ __forceinline__ uint32_t pk2_rne(float a, float b) {
  return (uint32_t)f2bf(a) | ((uint32_t)f2bf(b) << 16);
}

__device__ __forceinline__ void async16(const ushort_t* g, ushort_t* l) {
  // LDS dest is wave-uniform base; HW scatters lane i at base + i*16B.
  __builtin_amdgcn_global_load_lds(
      (const __attribute__((address_space(1))) uint32_t*)g,
      (__attribute__((address_space(3))) uint32_t*)l, 16, 0, 0);
}

// ---------------- prep: fp32 -> bf16 casts ----------------

__global__ void k_cvt_emb(const float* __restrict__ in, ushort_t* __restrict__ out) {
  int i = (blockIdx.x * 256 + threadIdx.x) * 4;
  float4 v = *(const float4*)(in + i);
  uint64_t pk = (uint64_t)f2bf(v.x) | ((uint64_t)f2bf(v.y) << 16) |
                ((uint64_t)f2bf(v.z) << 32) | ((uint64_t)f2bf(v.w) << 48);
  *(uint64_t*)(out + i) = pk;
}

// W (k-major [k][n]) -> Wt bf16 (n-major [n][k]); 4 weights via blockIdx.z
__global__ void k_cvt_w(const float* __restrict__ Wq, const float* __restrict__ Wk,
                        const float* __restrict__ Wv, const float* __restrict__ Wo,
                        ushort_t* __restrict__ Wt) {
  const float* W = (blockIdx.z == 0) ? Wq : (blockIdx.z == 1) ? Wk
                 : (blockIdx.z == 2) ? Wv : Wo;
  ushort_t* out = Wt + (size_t)blockIdx.z * D_ * D_;
  __shared__ float t[32][33];
  int k0 = blockIdx.x * 32, n0 = blockIdx.y * 32;
  int tx = threadIdx.x, ty = threadIdx.y;  // block (32,8)
  for (int r = 0; r < 32; r += 8)
    t[ty + r][tx] = W[(size_t)(k0 + ty + r) * D_ + n0 + tx];
  __syncthreads();
  for (int r = 0; r < 32; r += 8)
    out[(size_t)(n0 + ty + r) * D_ + k0 + tx] = f2bf(t[tx][ty + r]);
}

// mask -> order-preserving compaction map.  One wave per batch.
// pos[s] = compacted index (or -1 if masked); cntp[b] = count padded to 64;
// biasC[i] = bf16(-16) for i < cnt (fixed log2-softmax bound), bf16(-1e9) pad.
__global__ void k_mask_scan(const int* __restrict__ mask, int* __restrict__ pos,
                            ushort_t* __restrict__ biasC, int* __restrict__ cntp) {
  int b = blockIdx.x, lane = threadIdx.x;  // block 64
  int base = 0;
  for (int c = 0; c < 32; c++) {
    int s = c * 64 + lane;
    bool m = mask[b * S_ + s] != 0;
    unsigned long long bits = __ballot(m);
    int pre = base + __popcll(bits & ((1ull << lane) - 1ull));
    pos[b * S_ + s] = m ? pre : -1;
    base += __popcll(bits);
  }
  int cnt = base;
  for (int c = 0; c < 32; c++) {
    int i = c * 64 + lane;
    biasC[b * S_ + i] = (i < cnt) ? (ushort_t)0xC180 : (ushort_t)0xCE6E;
  }
  if (lane == 0) cntp[b] = (cnt + 63) & ~63;
}

// ---------------- swizzled bf16 NT GEMM core, BK=64 ----------------
// C[m][n] = sum_k A[m][k] * Bt[n][k]. Block tile: (IM*32) x 128, BK=64.
// LDS rows are 64 ushorts (8 chunks of 16B); chunk c of row r holds global
// chunk c ^ (r&7)  -> ds_read_b128 readers spread over all banks (conflict-free).
template <int IM>
__device__ __forceinline__ void gemm_core2(const ushort_t* __restrict__ A,
                                           const ushort_t* __restrict__ Bt,
                                           ushort_t* As, ushort_t* Bs,
                                           int m0, int n0, floatx4 (&acc)[IM][4]) {
  int t = threadIdx.x, lane = t & 63, w = t >> 6;
  int wm = (w >> 1) * (IM * 16), wn = (w & 1) * 64;
  int l15 = lane & 15, quad = lane >> 4;
  int srow8 = (lane >> 3) & 7;
  int sch = ((lane & 7) ^ srow8) * 8;                  // swizzled source chunk
  const ushort_t* Ag = A + (size_t)(m0 + w * 8 + srow8) * D_ + sch;
  const ushort_t* Bg = Bt + (size_t)(n0 + w * 8 + srow8) * D_ + sch;
  for (int kt = 0; kt < D_; kt += 64) {
    __syncthreads();
#pragma unroll
    for (int c = 0; c < IM; c++)
      async16(Ag + kt + (size_t)c * 32 * D_, As + (c * 32 + w * 8) * 64);
#pragma unroll
    for (int c = 0; c < 4; c++)
      async16(Bg + kt + (size_t)c * 32 * D_, Bs + (c * 32 + w * 8) * 64);
    __syncthreads();
#pragma unroll
    for (int ks = 0; ks < 2; ks++) {
      int ch = ((ks * 4 + quad) ^ (l15 & 7)) * 8;      // swizzled read chunk
      short8 a[IM], b[4];
#pragma unroll
      for (int i = 0; i < IM; i++)
        a[i] = *(const short8*)(As + (wm + i * 16 + l15) * 64 + ch);
#pragma unroll
      for (int j = 0; j < 4; j++)
        b[j] = *(const short8*)(Bs + (wn + j * 16 + l15) * 64 + ch);
#pragma unroll
      for (int i = 0; i < IM; i++)
#pragma unroll
        for (int j = 0; j < 4; j++)
          acc[i][j] = __builtin_amdgcn_mfma_f32_16x16x32_bf16(a[i], b[j], acc[i][j], 0, 0, 0);
    }
  }
}

// ---------------- QKV projection (z = 0/1/2 -> Q/K/V) ----------------
// K and V^T are written COMPACTED through pos[] (masked keys dropped).
__global__ __launch_bounds__(256, 3) void k_proj(
    const ushort_t* __restrict__ A, const ushort_t* __restrict__ Wt,
    const float* __restrict__ bq, const float* __restrict__ bk,
    const float* __restrict__ bv, const int* __restrict__ pos,
    ushort_t* __restrict__ Q, ushort_t* __restrict__ K, ushort_t* __restrict__ V) {
  __shared__ __align__(16) ushort_t As[128 * 64];
  __shared__ __align__(16) ushort_t Bs[128 * 64];
  int z = blockIdx.z;
  const ushort_t* Bt = Wt + (size_t)z * D_ * D_;
  const float* bias = (z == 0) ? bq : (z == 1) ? bk : bv;
  int m0 = blockIdx.x * 128, n0 = blockIdx.y * 128;
  floatx4 acc[4][4] = {};
  gemm_core2<4>(A, Bt, As, Bs, m0, n0, acc);
  int lane = threadIdx.x & 63, w = threadIdx.x >> 6;
  int wm = (w >> 1) * 64, wn = (w & 1) * 64;
  int quad = lane >> 4, l15 = lane & 15;
  // fold 1/sqrt(DQ) * log2(e) into Q (scores end up in log2 domain)
  float scale = 0.125f * 1.44269504f;
#pragma unroll
  for (int i = 0; i < 4; i++)
#pragma unroll
    for (int j = 0; j < 4; j++) {
      int ncol = n0 + wn + j * 16 + l15;
      float bb = bias[ncol];
      int h = ncol >> 6, dq = ncol & 63;
      int m = m0 + wm + i * 16 + quad * 4;
      int b = m >> 11, s = m & (S_ - 1);
      if (z == 0) {
#pragma unroll
        for (int r = 0; r < 4; r++)
          Q[((size_t)(b * H_ + h) * S_ + (s + r)) * DQ_ + dq] =
              f2bf((acc[i][j][r] + bb) * scale);
      } else {
        int4 p4 = *(const int4*)(pos + b * S_ + s);
#pragma unroll
        for (int r = 0; r < 4; r++) {
          int ps = (&p4.x)[r];
          if (ps >= 0) {
            float v = acc[i][j][r] + bb;
            if (z == 1) K[((size_t)(b * H_ + h) * S_ + ps) * DQ_ + dq] = f2bf(v);
            else        V[((size_t)(b * H_ + h) * DQ_ + dq) * S_ + ps] = f2bf(v);
          }
        }
      }
    }
}

// ---------------- flash attention over COMPACTED keys ----------------
// grid: (S_/128, B_*H_); block 256 = 4 waves; wave owns 32 q; trip = cntp[b]/64.
// R6's proven staged structure + bias folded in as an extra MFMA K-step
// (pad keys get bias -1e9 -> p = +0 exactly; real keys -16 = softmax bound).
// 32x32x16 MFMA layouts (verified m74/m101 family):
//   A frag: m = lane&31, k = (lane>>5)*8 + j ;  B frag: n = lane&31, same k
//   C/D: col = lane&31, row = (reg&3) + 8*(reg>>2) + 4*(lane>>5)
__global__ __launch_bounds__(256, 2) void k_attn(
    const ushort_t* __restrict__ Q, const ushort_t* __restrict__ Kc,
    const ushort_t* __restrict__ Vc, const ushort_t* __restrict__ biasC,
    const int* __restrict__ cntp, ushort_t* __restrict__ X) {
  int bh = blockIdx.y, b = bh >> 4, h = bh & 15;
  int t = threadIdx.x, lane = t & 63, w = t >> 6;
  int l31 = lane & 31, hi = lane >> 5;
  int q0 = blockIdx.x * 128 + w * 32;
  const ushort_t* Qh = Q + (size_t)bh * S_ * DQ_;
  const ushort_t* Kh = Kc + (size_t)bh * S_ * DQ_;
  const ushort_t* Vh = Vc + (size_t)bh * DQ_ * S_;
  const ushort_t* bbp = biasC + b * S_;
  int nk = cntp[b];

  __shared__ __align__(16) ushort_t Ks[64 * 64];      // [key][dq], chunk-swizzled
  __shared__ __align__(16) ushort_t Vs[64 * 64];      // [dq][key], chunk-swizzled

  // Q B-frags (pre-scaled by 0.125*log2e): per K=16 step, held for whole loop
  short8 qf[4];
#pragma unroll
  for (int ks = 0; ks < 4; ks++)
    qf[ks] = *(const short8*)(Qh + (size_t)(q0 + l31) * DQ_ + ks * 16 + hi * 8);

  // bias-step B-frag: 1.0 at k=0 only (hi==0, j==0)
  short8 qb = {};
  qb[0] = hi ? (short)0 : (short)0x3F80;   // bf16 1.0

  int srow8 = (lane >> 3) & 7;
  int sch = ((lane & 7) ^ srow8) * 8;                  // swizzled source chunk
  const ushort_t* Kg1 = Kh + (size_t)(w * 8 + srow8) * DQ_ + sch;
  const ushort_t* Vg1 = Vh + (size_t)(w * 8 + srow8) * S_ + sch;

  floatx16 o[2] = {};
  float lsum = 0.0f;

  for (int k0 = 0; k0 < nk; k0 += 64) {
    __syncthreads();
    async16(Kg1 + (size_t)k0 * DQ_, Ks + w * 512);
    async16(Kg1 + (size_t)(k0 + 32) * DQ_, Ks + w * 512 + 2048);
    async16(Vg1 + k0, Vs + w * 512);
    async16(Vg1 + (size_t)32 * S_ + k0, Vs + w * 512 + 2048);
    ushort_t bv0 = bbp[k0 + l31], bv1 = bbp[k0 + 32 + l31];
    __syncthreads();

    // S^T = K * Q^T + bias step  (col=q, row=key)
    floatx16 s0 = {}, s1 = {};
#pragma unroll
    for (int ks = 0; ks < 4; ks++) {
      int ch = ((ks * 2 + hi) ^ (l31 & 7)) * 8;
      short8 kf0 = *(const short8*)(Ks + l31 * 64 + ch);
      short8 kf1 = *(const short8*)(Ks + (32 + l31) * 64 + ch);
      s0 = __builtin_amdgcn_mfma_f32_32x32x16_bf16(kf0, qf[ks], s0, 0, 0, 0);
      s1 = __builtin_amdgcn_mfma_f32_32x32x16_bf16(kf1, qf[ks], s1, 0, 0, 0);
    }
    short8 kb0 = {}, kb1 = {};
    kb0[0] = hi ? (short)0 : (short)bv0;
    kb1[0] = hi ? (short)0 : (short)bv1;
    s0 = __builtin_amdgcn_mfma_f32_32x32x16_bf16(kb0, qb, s0, 0, 0, 0);
    s1 = __builtin_amdgcn_mfma_f32_32x32x16_bf16(kb1, qb, s1, 0, 0, 0);

    // p = 2^s (bias already added); pack to bf16 dwords in registers.
    // reg r=4g+j of acc a holds key = a*32 + 8g + 4*hi + j  (col q = l31)
    uint32_t pk[2][4][2];
#pragma unroll
    for (int g = 0; g < 4; g++) {
      float p0[4], p1[4];
#pragma unroll
      for (int j = 0; j < 4; j++) {
        p0[j] = EXP2(s0[g * 4 + j]);
        p1[j] = EXP2(s1[g * 4 + j]);
        lsum += p0[j] + p1[j];
      }
      pk[0][g][0] = pk2_trunc(p0[0], p0[1]); pk[0][g][1] = pk2_trunc(p0[2], p0[3]);
      pk[1][g][0] = pk2_trunc(p1[0], p1[1]); pk[1][g][1] = pk2_trunc(p1[2], p1[3]);
    }

    // O^T += V^T * P^T : A = V^T rows (dq), B = P^T built from regs.
    // Frag ks needs keys ks*16 + hi*8 + {0..7}; partner half via shfl_xor(32).
#pragma unroll
    for (int ks = 0; ks < 4; ks++) {
      int a = ks >> 1, gb = (ks & 1) * 2;
      uint32_t pass0 = hi ? pk[a][gb][0]     : pk[a][gb + 1][0];
      uint32_t pass1 = hi ? pk[a][gb][1]     : pk[a][gb + 1][1];
      uint32_t own0  = hi ? pk[a][gb + 1][0] : pk[a][gb][0];
      uint32_t own1  = hi ? pk[a][gb + 1][1] : pk[a][gb][1];
      uint32_t recv0 = __shfl_xor(pass0, 32, 64);
      uint32_t recv1 = __shfl_xor(pass1, 32, 64);
      union { uint32_t u[4]; short8 v; } pf;
      pf.u[0] = hi ? recv0 : own0;   // hi_src=0: keys +0..3
      pf.u[1] = hi ? recv1 : own1;
      pf.u[2] = hi ? own0 : recv0;   // hi_src=1: keys +4..7
      pf.u[3] = hi ? own1 : recv1;
      int ch = ((ks * 2 + hi) ^ (l31 & 7)) * 8;
      short8 vf0 = *(const short8*)(Vs + l31 * 64 + ch);
      short8 vf1 = *(const short8*)(Vs + (32 + l31) * 64 + ch);
      o[0] = __builtin_amdgcn_mfma_f32_32x32x16_bf16(vf0, pf.v, o[0], 0, 0, 0);
      o[1] = __builtin_amdgcn_mfma_f32_32x32x16_bf16(vf1, pf.v, o[1], 0, 0, 0);
    }
  }

  // epilogue: l(q) = own-half sum + partner-half sum; packed 8B stores
  float l = lsum + __shfl_xor(lsum, 32, 64);
  float inv = 1.0f / l;
  int q = q0 + l31;
  size_t base = (size_t)(b * S_ + q) * D_ + h * DQ_;
#pragma unroll
  for (int a = 0; a < 2; a++)
#pragma unroll
    for (int g = 0; g < 4; g++) {
      uint2 st;
      st.x = pk2_rne(o[a][4 * g] * inv, o[a][4 * g + 1] * inv);
      st.y = pk2_rne(o[a][4 * g + 2] * inv, o[a][4 * g + 3] * inv);
      *(uint2*)(X + base + a * 32 + g * 8 + 4 * hi) = st;
    }
}

// ---------------- output projection (fp32 out), 64x128 tile ----------------
__global__ __launch_bounds__(256, 2) void k_oproj(
    const ushort_t* __restrict__ A, const ushort_t* __restrict__ Wt,
    const float* __restrict__ bias, float* __restrict__ C) {
  __shared__ __align__(16) ushort_t As[64 * 64];
  __shared__ __align__(16) ushort_t Bs[128 * 64];
  int m0 = blockIdx.x * 64, n0 = blockIdx.y * 128;
  floatx4 acc[2][4] = {};
  gemm_core2<2>(A, Wt, As, Bs, m0, n0, acc);
  int lane = threadIdx.x & 63, w = threadIdx.x >> 6;
  int wm = (w >> 1) * 32, wn = (w & 1) * 64;
  int quad = lane >> 4, l15 = lane & 15;
#pragma unroll
  for (int i = 0; i < 2; i++)
#pragma unroll
    for (int j = 0; j < 4; j++) {
      int ncol = n0 + wn + j * 16 + l15;
      float bb = bias[ncol];
      int mr = m0 + wm + i * 16 + quad * 4;
#pragma unroll
      for (int r = 0; r < 4; r++)
        C[(size_t)(mr + r) * D_ + ncol] = acc[i][j][r] + bb;
    }
}

extern "C" void kernel_launch(void* const* d_in, const int* in_sizes, int n_in,
                              void* d_out, int out_size, void* d_ws, size_t ws_size,
                              hipStream_t stream) {
  const float* emb  = (const float*)d_in[0];
  const int*   mask = (const int*)d_in[1];
  const float* Wq = (const float*)d_in[2];
  const float* bq = (const float*)d_in[3];
  const float* Wk = (const float*)d_in[4];
  const float* bk = (const float*)d_in[5];
  const float* Wv = (const float*)d_in[6];
  const float* bv = (const float*)d_in[7];
  const float* Wo = (const float*)d_in[8];
  const float* bo = (const float*)d_in[9];
  float* out = (float*)d_out;

  ushort_t* embb  = (ushort_t*)d_ws;                 // 4096x1024 bf16
  ushort_t* Wt    = embb + (size_t)M_ * D_;          // 4 x 1024x1024 bf16 (transposed)
  ushort_t* Qb    = Wt + (size_t)4 * D_ * D_;        // [b,h,s,dq]  (pre-scaled)
  ushort_t* Kb    = Qb + (size_t)M_ * D_;            // [b,h,kc,dq] compacted
  ushort_t* Vb    = Kb + (size_t)M_ * D_;            // [b,h,dq,kc] compacted V^T
  ushort_t* Xb    = Vb + (size_t)M_ * D_;            // [b*s, h*dq]
  ushort_t* biasC = Xb + (size_t)M_ * D_;            // [B_][S_] bf16 bias
  int* pos        = (int*)(biasC + (size_t)B_ * S_); // [B_][S_] compaction map
  int* cntp       = pos + B_ * S_;                   // [B_] padded counts

  k_cvt_emb<<<dim3(M_ * D_ / 1024), 256, 0, stream>>>(emb, embb);
  k_cvt_w<<<dim3(32, 32, 4), dim3(32, 8), 0, stream>>>(Wq, Wk, Wv, Wo, Wt);
  k_mask_scan<<<dim3(B_), 64, 0, stream>>>(mask, pos, biasC, cntp);
  k_proj<<<dim3(32, 8, 3), 256, 0, stream>>>(embb, Wt, bq, bk, bv, pos, Qb, Kb, Vb);
  k_attn<<<dim3(16, 32), 256, 0, stream>>>(Qb, Kb, Vb, biasC, cntp, Xb);
  k_oproj<<<dim3(64, 8), 256, 0, stream>>>(Xb, Wt + (size_t)3 * D_ * D_, bo, out);
}

// Round 9
// 178.635 us; speedup vs baseline: 1.4664x; 1.0430x over previous
//
#include <hip/hip_runtime.h>
#include <stdint.h>

#define B_ 2
#define S_ 2048
#define D_ 1024
#define H_ 16
#define DQ_ 64
#define M_ 4096            // B_*S_

typedef unsigned short ushort_t;
typedef __attribute__((ext_vector_type(8))) short short8;    // 8 bf16 (4 VGPRs)
typedef __attribute__((ext_vector_type(4))) float floatx4;   // MFMA 16x16 C/D
typedef __attribute__((ext_vector_type(16))) float floatx16; // MFMA 32x32 C/D

#if __has_builtin(__builtin_amdgcn_exp2f)
#define EXP2(x) __builtin_amdgcn_exp2f(x)
#else
#define EXP2(x) exp2f(x)
#endif

__device__ __forceinline__ ushort_t f2bf(float f) {
  union { float f; uint32_t u; } v; v.f = f;
  uint32_t r = v.u + 0x7FFFu + ((v.u >> 16) & 1u);  // RNE
  return (ushort_t)(r >> 16);
}

// pack two f32 -> two bf16 (truncation; bias cancels in softmax ratio)
__device__ __forceinline__ uint32_t pk2_trunc(float a, float b) {
  union { float f; uint32_t u; } va, vb; va.f = a; vb.f = b;
  return (va.u >> 16) | (vb.u & 0xFFFF0000u);
}
__device__ __forceinline__ uint32_t pk2_rne(float a, float b) {
  return (uint32_t)f2bf(a) | ((uint32_t)f2bf(b) << 16);
}

__device__ __forceinline__ void async16(const ushort_t* g, ushort_t* l) {
  // LDS dest is wave-uniform base; HW scatters lane i at base + i*16B.
  __builtin_amdgcn_global_load_lds(
      (const __attribute__((address_space(1))) uint32_t*)g,
      (__attribute__((address_space(3))) uint32_t*)l, 16, 0, 0);
}

// ---------------- fused prep: emb cast | W transpose | mask scan ----------------
// grid 8194 x 256:
//   [0,4096)    : emb fp32 -> bf16 (4 elems/thread)
//   [4096,8192) : W [k][n] fp32 -> Wt bf16 [n][k]  (1024 blocks per weight, 4 weights)
//   8192+b      : order-preserving mask compaction scan for batch b (wave 0 only)
__global__ void k_prep(const float* __restrict__ emb, const float* __restrict__ Wq,
                       const float* __restrict__ Wk, const float* __restrict__ Wv,
                       const float* __restrict__ Wo, const int* __restrict__ mask,
                       ushort_t* __restrict__ embb, ushort_t* __restrict__ Wt,
                       int* __restrict__ pos, ushort_t* __restrict__ biasC,
                       int* __restrict__ cntp) {
  __shared__ float t[32][33];
  int blk = blockIdx.x, tid = threadIdx.x;
  if (blk < 4096) {
    int i = (blk * 256 + tid) * 4;
    float4 v = *(const float4*)(emb + i);
    uint64_t pk = (uint64_t)f2bf(v.x) | ((uint64_t)f2bf(v.y) << 16) |
                  ((uint64_t)f2bf(v.z) << 32) | ((uint64_t)f2bf(v.w) << 48);
    *(uint64_t*)(embb + i) = pk;
  } else if (blk < 8192) {
    int widx = blk - 4096;
    int z = widx >> 10, tt = widx & 1023;
    const float* W = (z == 0) ? Wq : (z == 1) ? Wk : (z == 2) ? Wv : Wo;
    ushort_t* out = Wt + (size_t)z * D_ * D_;
    int k0 = (tt >> 5) * 32, n0 = (tt & 31) * 32;
    int tx = tid & 31, ty = tid >> 5;  // 32 x 8
    for (int r = 0; r < 32; r += 8)
      t[ty + r][tx] = W[(size_t)(k0 + ty + r) * D_ + n0 + tx];
    __syncthreads();
    for (int r = 0; r < 32; r += 8)
      out[(size_t)(n0 + ty + r) * D_ + k0 + tx] = f2bf(t[tx][ty + r]);
  } else if (tid < 64) {
    // pos[s] = compacted index (-1 if masked); cntp[b] = count padded to 64;
    // biasC[i] = bf16(-16) real key (log2-softmax bound), bf16(-1e9) pad.
    int b = blk - 8192, lane = tid;
    int base = 0;
    for (int c = 0; c < 32; c++) {
      int s = c * 64 + lane;
      bool m = mask[b * S_ + s] != 0;
      unsigned long long bits = __ballot(m);
      int pre = base + __popcll(bits & ((1ull << lane) - 1ull));
      pos[b * S_ + s] = m ? pre : -1;
      base += __popcll(bits);
    }
    int cnt = base;
    for (int c = 0; c < 32; c++) {
      int i = c * 64 + lane;
      biasC[b * S_ + i] = (i < cnt) ? (ushort_t)0xC180 : (ushort_t)0xCE6E;
    }
    if (lane == 0) cntp[b] = (cnt + 63) & ~63;
  }
}

// ---------------- swizzled bf16 NT GEMM core, BK=64 ----------------
// C[m][n] = sum_k A[m][k] * Bt[n][k]. Block tile: (IM*32) x 128, BK=64.
// LDS rows are 64 ushorts (8 chunks of 16B); chunk c of row r holds global
// chunk c ^ (r&7)  -> ds_read_b128 readers spread over all banks (conflict-free).
template <int IM>
__device__ __forceinline__ void gemm_core2(const ushort_t* __restrict__ A,
                                           const ushort_t* __restrict__ Bt,
                                           ushort_t* As, ushort_t* Bs,
                                           int m0, int n0, floatx4 (&acc)[IM][4]) {
  int t = threadIdx.x, lane = t & 63, w = t >> 6;
  int wm = (w >> 1) * (IM * 16), wn = (w & 1) * 64;
  int l15 = lane & 15, quad = lane >> 4;
  int srow8 = (lane >> 3) & 7;
  int sch = ((lane & 7) ^ srow8) * 8;                  // swizzled source chunk
  const ushort_t* Ag = A + (size_t)(m0 + w * 8 + srow8) * D_ + sch;
  const ushort_t* Bg = Bt + (size_t)(n0 + w * 8 + srow8) * D_ + sch;
  for (int kt = 0; kt < D_; kt += 64) {
    __syncthreads();
#pragma unroll
    for (int c = 0; c < IM; c++)
      async16(Ag + kt + (size_t)c * 32 * D_, As + (c * 32 + w * 8) * 64);
#pragma unroll
    for (int c = 0; c < 4; c++)
      async16(Bg + kt + (size_t)c * 32 * D_, Bs + (c * 32 + w * 8) * 64);
    __syncthreads();
#pragma unroll
    for (int ks = 0; ks < 2; ks++) {
      int ch = ((ks * 4 + quad) ^ (l15 & 7)) * 8;      // swizzled read chunk
      short8 a[IM], b[4];
#pragma unroll
      for (int i = 0; i < IM; i++)
        a[i] = *(const short8*)(As + (wm + i * 16 + l15) * 64 + ch);
#pragma unroll
      for (int j = 0; j < 4; j++)
        b[j] = *(const short8*)(Bs + (wn + j * 16 + l15) * 64 + ch);
#pragma unroll
      for (int i = 0; i < IM; i++)
#pragma unroll
        for (int j = 0; j < 4; j++)
          acc[i][j] = __builtin_amdgcn_mfma_f32_16x16x32_bf16(a[i], b[j], acc[i][j], 0, 0, 0);
    }
  }
}

// ---------------- QKV projection (z = 0/1/2 -> Q/K/V) ----------------
// K and V^T are written COMPACTED through pos[] (masked keys dropped).
__global__ __launch_bounds__(256, 3) void k_proj(
    const ushort_t* __restrict__ A, const ushort_t* __restrict__ Wt,
    const float* __restrict__ bq, const float* __restrict__ bk,
    const float* __restrict__ bv, const int* __restrict__ pos,
    ushort_t* __restrict__ Q, ushort_t* __restrict__ K, ushort_t* __restrict__ V) {
  __shared__ __align__(16) ushort_t As[128 * 64];
  __shared__ __align__(16) ushort_t Bs[128 * 64];
  int z = blockIdx.z;
  const ushort_t* Bt = Wt + (size_t)z * D_ * D_;
  const float* bias = (z == 0) ? bq : (z == 1) ? bk : bv;
  int m0 = blockIdx.x * 128, n0 = blockIdx.y * 128;
  floatx4 acc[4][4] = {};
  gemm_core2<4>(A, Bt, As, Bs, m0, n0, acc);
  int lane = threadIdx.x & 63, w = threadIdx.x >> 6;
  int wm = (w >> 1) * 64, wn = (w & 1) * 64;
  int quad = lane >> 4, l15 = lane & 15;
  // fold 1/sqrt(DQ) * log2(e) into Q (scores end up in log2 domain)
  float scale = 0.125f * 1.44269504f;
#pragma unroll
  for (int i = 0; i < 4; i++)
#pragma unroll
    for (int j = 0; j < 4; j++) {
      int ncol = n0 + wn + j * 16 + l15;
      float bb = bias[ncol];
      int h = ncol >> 6, dq = ncol & 63;
      int m = m0 + wm + i * 16 + quad * 4;
      int b = m >> 11, s = m & (S_ - 1);
      if (z == 0) {
#pragma unroll
        for (int r = 0; r < 4; r++)
          Q[((size_t)(b * H_ + h) * S_ + (s + r)) * DQ_ + dq] =
              f2bf((acc[i][j][r] + bb) * scale);
      } else {
        int4 p4 = *(const int4*)(pos + b * S_ + s);
#pragma unroll
        for (int r = 0; r < 4; r++) {
          int ps = (&p4.x)[r];
          if (ps >= 0) {
            float v = acc[i][j][r] + bb;
            if (z == 1) K[((size_t)(b * H_ + h) * S_ + ps) * DQ_ + dq] = f2bf(v);
            else        V[((size_t)(b * H_ + h) * DQ_ + dq) * S_ + ps] = f2bf(v);
          }
        }
      }
    }
}

// ---------------- flash attention over COMPACTED keys ----------------
// grid: (S_/128, B_*H_); block 256 = 4 waves; wave owns 32 q; trip = cntp[b]/64.
// Staged structure + bias folded in as an extra MFMA K-step
// (pad keys get bias -1e9 -> p = +0 exactly; real keys -16 = softmax bound).
// 32x32x16 MFMA layouts (verified m74/m101 family):
//   A frag: m = lane&31, k = (lane>>5)*8 + j ;  B frag: n = lane&31, same k
//   C/D: col = lane&31, row = (reg&3) + 8*(reg>>2) + 4*(lane>>5)
__global__ __launch_bounds__(256, 2) void k_attn(
    const ushort_t* __restrict__ Q, const ushort_t* __restrict__ Kc,
    const ushort_t* __restrict__ Vc, const ushort_t* __restrict__ biasC,
    const int* __restrict__ cntp, ushort_t* __restrict__ X) {
  int bh = blockIdx.y, b = bh >> 4, h = bh & 15;
  int t = threadIdx.x, lane = t & 63, w = t >> 6;
  int l31 = lane & 31, hi = lane >> 5;
  int q0 = blockIdx.x * 128 + w * 32;
  const ushort_t* Qh = Q + (size_t)bh * S_ * DQ_;
  const ushort_t* Kh = Kc + (size_t)bh * S_ * DQ_;
  const ushort_t* Vh = Vc + (size_t)bh * DQ_ * S_;
  const ushort_t* bbp = biasC + b * S_;
  int nk = cntp[b];

  __shared__ __align__(16) ushort_t Ks[64 * 64];      // [key][dq], chunk-swizzled
  __shared__ __align__(16) ushort_t Vs[64 * 64];      // [dq][key], chunk-swizzled

  // Q B-frags (pre-scaled by 0.125*log2e): per K=16 step, held for whole loop
  short8 qf[4];
#pragma unroll
  for (int ks = 0; ks < 4; ks++)
    qf[ks] = *(const short8*)(Qh + (size_t)(q0 + l31) * DQ_ + ks * 16 + hi * 8);

  // bias-step B-frag: 1.0 at k=0 only (hi==0, j==0)
  short8 qb = {};
  qb[0] = hi ? (short)0 : (short)0x3F80;   // bf16 1.0

  int srow8 = (lane >> 3) & 7;
  int sch = ((lane & 7) ^ srow8) * 8;                  // swizzled source chunk
  const ushort_t* Kg1 = Kh + (size_t)(w * 8 + srow8) * DQ_ + sch;
  const ushort_t* Vg1 = Vh + (size_t)(w * 8 + srow8) * S_ + sch;

  floatx16 o[2] = {};
  float lsum = 0.0f;

  for (int k0 = 0; k0 < nk; k0 += 64) {
    __syncthreads();
    async16(Kg1 + (size_t)k0 * DQ_, Ks + w * 512);
    async16(Kg1 + (size_t)(k0 + 32) * DQ_, Ks + w * 512 + 2048);
    async16(Vg1 + k0, Vs + w * 512);
    async16(Vg1 + (size_t)32 * S_ + k0, Vs + w * 512 + 2048);
    ushort_t bv0 = bbp[k0 + l31], bv1 = bbp[k0 + 32 + l31];
    __syncthreads();

    // S^T = K * Q^T + bias step  (col=q, row=key)
    floatx16 s0 = {}, s1 = {};
#pragma unroll
    for (int ks = 0; ks < 4; ks++) {
      int ch = ((ks * 2 + hi) ^ (l31 & 7)) * 8;
      short8 kf0 = *(const short8*)(Ks + l31 * 64 + ch);
      short8 kf1 = *(const short8*)(Ks + (32 + l31) * 64 + ch);
      s0 = __builtin_amdgcn_mfma_f32_32x32x16_bf16(kf0, qf[ks], s0, 0, 0, 0);
      s1 = __builtin_amdgcn_mfma_f32_32x32x16_bf16(kf1, qf[ks], s1, 0, 0, 0);
    }
    short8 kb0 = {}, kb1 = {};
    kb0[0] = hi ? (short)0 : (short)bv0;
    kb1[0] = hi ? (short)0 : (short)bv1;
    s0 = __builtin_amdgcn_mfma_f32_32x32x16_bf16(kb0, qb, s0, 0, 0, 0);
    s1 = __builtin_amdgcn_mfma_f32_32x32x16_bf16(kb1, qb, s1, 0, 0, 0);

    // p = 2^s (bias already added); pack to bf16 dwords in registers.
    // reg r=4g+j of acc a holds key = a*32 + 8g + 4*hi + j  (col q = l31)
    uint32_t pk[2][4][2];
#pragma unroll
    for (int g = 0; g < 4; g++) {
      float p0[4], p1[4];
#pragma unroll
      for (int j = 0; j < 4; j++) {
        p0[j] = EXP2(s0[g * 4 + j]);
        p1[j] = EXP2(s1[g * 4 + j]);
        lsum += p0[j] + p1[j];
      }
      pk[0][g][0] = pk2_trunc(p0[0], p0[1]); pk[0][g][1] = pk2_trunc(p0[2], p0[3]);
      pk[1][g][0] = pk2_trunc(p1[0], p1[1]); pk[1][g][1] = pk2_trunc(p1[2], p1[3]);
    }

    // O^T += V^T * P^T : A = V^T rows (dq), B = P^T built from regs.
    // Frag ks needs keys ks*16 + hi*8 + {0..7}; partner half via shfl_xor(32).
#pragma unroll
    for (int ks = 0; ks < 4; ks++) {
      int a = ks >> 1, gb = (ks & 1) * 2;
      uint32_t pass0 = hi ? pk[a][gb][0]     : pk[a][gb + 1][0];
      uint32_t pass1 = hi ? pk[a][gb][1]     : pk[a][gb + 1][1];
      uint32_t own0  = hi ? pk[a][gb + 1][0] : pk[a][gb][0];
      uint32_t own1  = hi ? pk[a][gb + 1][1] : pk[a][gb][1];
      uint32_t recv0 = __shfl_xor(pass0, 32, 64);
      uint32_t recv1 = __shfl_xor(pass1, 32, 64);
      union { uint32_t u[4]; short8 v; } pf;
      pf.u[0] = hi ? recv0 : own0;   // hi_src=0: keys +0..3
      pf.u[1] = hi ? recv1 : own1;
      pf.u[2] = hi ? own0 : recv0;   // hi_src=1: keys +4..7
      pf.u[3] = hi ? own1 : recv1;
      int ch = ((ks * 2 + hi) ^ (l31 & 7)) * 8;
      short8 vf0 = *(const short8*)(Vs + l31 * 64 + ch);
      short8 vf1 = *(const short8*)(Vs + (32 + l31) * 64 + ch);
      o[0] = __builtin_amdgcn_mfma_f32_32x32x16_bf16(vf0, pf.v, o[0], 0, 0, 0);
      o[1] = __builtin_amdgcn_mfma_f32_32x32x16_bf16(vf1, pf.v, o[1], 0, 0, 0);
    }
  }

  // epilogue: l(q) = own-half sum + partner-half sum; packed 8B stores
  float l = lsum + __shfl_xor(lsum, 32, 64);
  float inv = 1.0f / l;
  int q = q0 + l31;
  size_t base = (size_t)(b * S_ + q) * D_ + h * DQ_;
#pragma unroll
  for (int a = 0; a < 2; a++)
#pragma unroll
    for (int g = 0; g < 4; g++) {
      uint2 st;
      st.x = pk2_rne(o[a][4 * g] * inv, o[a][4 * g + 1] * inv);
      st.y = pk2_rne(o[a][4 * g + 2] * inv, o[a][4 * g + 3] * inv);
      *(uint2*)(X + base + a * 32 + g * 8 + 4 * hi) = st;
    }
}

// ---------------- output projection (fp32 out), 64x128 tile ----------------
__global__ __launch_bounds__(256, 2) void k_oproj(
    const ushort_t* __restrict__ A, const ushort_t* __restrict__ Wt,
    const float* __restrict__ bias, float* __restrict__ C) {
  __shared__ __align__(16) ushort_t As[64 * 64];
  __shared__ __align__(16) ushort_t Bs[128 * 64];
  int m0 = blockIdx.x * 64, n0 = blockIdx.y * 128;
  floatx4 acc[2][4] = {};
  gemm_core2<2>(A, Wt, As, Bs, m0, n0, acc);
  int lane = threadIdx.x & 63, w = threadIdx.x >> 6;
  int wm = (w >> 1) * 32, wn = (w & 1) * 64;
  int quad = lane >> 4, l15 = lane & 15;
#pragma unroll
  for (int i = 0; i < 2; i++)
#pragma unroll
    for (int j = 0; j < 4; j++) {
      int ncol = n0 + wn + j * 16 + l15;
      float bb = bias[ncol];
      int mr = m0 + wm + i * 16 + quad * 4;
#pragma unroll
      for (int r = 0; r < 4; r++)
        C[(size_t)(mr + r) * D_ + ncol] = acc[i][j][r] + bb;
    }
}

extern "C" void kernel_launch(void* const* d_in, const int* in_sizes, int n_in,
                              void* d_out, int out_size, void* d_ws, size_t ws_size,
                              hipStream_t stream) {
  const float* emb  = (const float*)d_in[0];
  const int*   mask = (const int*)d_in[1];
  const float* Wq = (const float*)d_in[2];
  const float* bq = (const float*)d_in[3];
  const float* Wk = (const float*)d_in[4];
  const float* bk = (const float*)d_in[5];
  const float* Wv = (const float*)d_in[6];
  const float* bv = (const float*)d_in[7];
  const float* Wo = (const float*)d_in[8];
  const float* bo = (const float*)d_in[9];
  float* out = (float*)d_out;

  ushort_t* embb  = (ushort_t*)d_ws;                 // 4096x1024 bf16
  ushort_t* Wt    = embb + (size_t)M_ * D_;          // 4 x 1024x1024 bf16 (transposed)
  ushort_t* Qb    = Wt + (size_t)4 * D_ * D_;        // [b,h,s,dq]  (pre-scaled)
  ushort_t* Kb    = Qb + (size_t)M_ * D_;            // [b,h,kc,dq] compacted
  ushort_t* Vb    = Kb + (size_t)M_ * D_;            // [b,h,dq,kc] compacted V^T
  ushort_t* Xb    = Vb + (size_t)M_ * D_;            // [b*s, h*dq]
  ushort_t* biasC = Xb + (size_t)M_ * D_;            // [B_][S_] bf16 bias
  int* pos        = (int*)(biasC + (size_t)B_ * S_); // [B_][S_] compaction map
  int* cntp       = pos + B_ * S_;                   // [B_] padded counts

  k_prep<<<dim3(8192 + B_), 256, 0, stream>>>(emb, Wq, Wk, Wv, Wo, mask,
                                              embb, Wt, pos, biasC, cntp);
  k_proj<<<dim3(32, 8, 3), 256, 0, stream>>>(embb, Wt, bq, bk, bv, pos, Qb, Kb, Vb);
  k_attn<<<dim3(16, 32), 256, 0, stream>>>(Qb, Kb, Vb, biasC, cntp, Xb);
  k_oproj<<<dim3(64, 8), 256, 0, stream>>>(Xb, Wt + (size_t)3 * D_ * D_, bo, out);
}